// Round 1
// baseline (331.635 us; speedup 1.0000x reference)
//
#include <hip/hip_runtime.h>

// EdgeConvE: B=4, V=1024, C=64, E=16, K=32, OUT=128
// Algebraic refactor:
//   feat = [x_src, x_dst - x_src, e]  =>  feat@W = x_src@(Wa-Wb) + x_dst@Wb + e@Wc
//   nt[n] = b + x[n]@(Wa-Wb)   (per node, kernel A)
//   y [n] = x[n]@Wb            (per node, kernel A)
//   out[node] = max_e relu(nt[src] + y[dst_e] + eattr_e@Wc)   (kernel B)
// relu folds into the max by initializing the running max to 0.

#define NN 4096      // B*V nodes
#define KE 32        // edges per node
#define OUTF 128

__global__ __launch_bounds__(256) void node_pre(
    const float* __restrict__ x,    // [NN, 64]
    const float* __restrict__ W,    // [144, 128] row-major
    const float* __restrict__ bias, // [128]
    float* __restrict__ nt,         // [NN, 128]
    float* __restrict__ yv)         // [NN, 128]
{
    __shared__ float xs[16][64];    // 4 KB
    const int t  = threadIdx.x;
    const int nb = blockIdx.x * 16; // 256 blocks x 16 nodes

    // stage 16 node rows: 1024 floats, float4 per thread
    {
        int idx = t * 4;            // 0..1020
        if (idx < 1024)
            *(float4*)&xs[idx >> 6][idx & 63] = *(const float4*)&x[nb * 64 + idx];
    }
    __syncthreads();

    const int j = t & 127;          // output column
    const int h = t >> 7;           // 0/1 -> node half
    float accN[8], accY[8];
#pragma unroll
    for (int i = 0; i < 8; i++) { accN[i] = 0.f; accY[i] = 0.f; }

#pragma unroll 4
    for (int c = 0; c < 64; c++) {
        float wa = W[c * 128 + j];          // rows 0..63   (Wa)
        float wb = W[(64 + c) * 128 + j];   // rows 64..127 (Wb)
        float wd = wa - wb;
#pragma unroll
        for (int i = 0; i < 8; i++) {
            float xv = xs[h * 8 + i][c];    // LDS broadcast within wave
            accN[i] = fmaf(xv, wd, accN[i]);
            accY[i] = fmaf(xv, wb, accY[i]);
        }
    }
    float bj = bias[j];
#pragma unroll
    for (int i = 0; i < 8; i++) {
        int node = nb + h * 8 + i;
        nt[node * 128 + j] = accN[i] + bj;
        yv[node * 128 + j] = accY[i];
    }
}

__global__ __launch_bounds__(256) void edge_max(
    const float* __restrict__ ea,   // [4,1024,1024,16]
    const float* __restrict__ W,    // [144,128]
    const int*   __restrict__ dst,  // [NN*KE] global dst node ids
    const float* __restrict__ nt,   // [NN,128]
    const float* __restrict__ yv,   // [NN,128]
    float* __restrict__ out)        // [NN,128]
{
    __shared__ int   dstL[KE];
    __shared__ float eaL[KE][16];   // 2 KB
    __shared__ float red[8][128];   // 4 KB

    const int t    = threadIdx.x;
    const int n    = blockIdx.x;    // node id, one block per node
    const int bidx = n >> 10;
    const int vi   = n & 1023;

    if (t < KE) dstL[t] = dst[n * KE + t];
    __syncthreads();

    // stage eattr rows for the 32 neighbors: 512 floats, float2 per thread
    {
        int idx = t * 2;            // 0..510
        int e   = idx >> 4;
        int k   = idx & 15;
        int ui  = dstL[e] & 1023;
        const float* p = &ea[(((size_t)bidx * 1024 + vi) * 1024 + ui) * 16 + k];
        *(float2*)&eaL[e][k] = *(const float2*)p;
    }

    const int cg = t & 31;          // column group: cols 4*cg..4*cg+3
    const int es = t >> 5;          // edge slice 0..7

    // Wc (rows 128..143) for this thread's 4 columns: 64 VGPRs, reused 4 edges
    float4 wc[16];
#pragma unroll
    for (int k = 0; k < 16; k++)
        wc[k] = *(const float4*)&W[(128 + k) * 128 + cg * 4];
    float4 ntr = *(const float4*)&nt[n * 128 + cg * 4];

    __syncthreads();

    float4 vmax = {0.f, 0.f, 0.f, 0.f};  // relu folded: max(0, ...)
#pragma unroll
    for (int ee = 0; ee < 4; ee++) {
        int e = es + ee * 8;
        int d = dstL[e];
        float4 y4 = *(const float4*)&yv[d * 128 + cg * 4];
        float4 acc;
        acc.x = ntr.x + y4.x;
        acc.y = ntr.y + y4.y;
        acc.z = ntr.z + y4.z;
        acc.w = ntr.w + y4.w;
#pragma unroll
        for (int k = 0; k < 16; k++) {
            float eav = eaL[e][k];          // LDS broadcast (uniform per half-wave)
            acc.x = fmaf(eav, wc[k].x, acc.x);
            acc.y = fmaf(eav, wc[k].y, acc.y);
            acc.z = fmaf(eav, wc[k].z, acc.z);
            acc.w = fmaf(eav, wc[k].w, acc.w);
        }
        vmax.x = fmaxf(vmax.x, acc.x);
        vmax.y = fmaxf(vmax.y, acc.y);
        vmax.z = fmaxf(vmax.z, acc.z);
        vmax.w = fmaxf(vmax.w, acc.w);
    }

    *(float4*)&red[es][cg * 4] = vmax;
    __syncthreads();

    if (t < 128) {
        float m = red[0][t];
#pragma unroll
        for (int s = 1; s < 8; s++) m = fmaxf(m, red[s][t]);
        out[n * 128 + t] = m;
    }
}

extern "C" void kernel_launch(void* const* d_in, const int* in_sizes, int n_in,
                              void* d_out, int out_size, void* d_ws, size_t ws_size,
                              hipStream_t stream) {
    const float* x    = (const float*)d_in[0];  // node_features [4,1024,64]
    const float* ea   = (const float*)d_in[1];  // edge_attributes [4,1024,1024,16]
    const float* W    = (const float*)d_in[2];  // [144,128]
    const float* bias = (const float*)d_in[3];  // [128]
    const int*   dst  = (const int*)d_in[5];    // [131072]
    float* out = (float*)d_out;

    float* nt = (float*)d_ws;                   // [NN,128] = 2 MB
    float* yv = nt + (size_t)NN * OUTF;         // [NN,128] = 2 MB

    hipLaunchKernelGGL(node_pre, dim3(256), dim3(256), 0, stream, x, W, bias, nt, yv);
    hipLaunchKernelGGL(edge_max, dim3(NN), dim3(256), 0, stream, ea, W, dst, nt, yv, out);
}

// Round 3
// 329.282 us; speedup vs baseline: 1.0071x; 1.0071x over previous
//
#include <hip/hip_runtime.h>
#include <float.h>

// EdgeConvE: B=4, V=1024, C=64, E=16, K=32, OUT=128
// Algebra: feat@W = x_src@(Wa-Wb) + x_dst@Wb + e@Wc
//   nt[n] = b + x[n]@(Wa-Wb);  y[n] = x[n]@Wb         (kernel A, per node)
//   out[n] = relu(nt[n] + max_e (y[dst_e] + e@Wc))    (kernel B)
// (max_e relu(a+t_e) == relu(a+max_e t_e): relu monotone, so nt-add + relu
//  hoist out of the edge loop.)

#define NN 4096
#define KE 32
#define OUTF 128

__global__ __launch_bounds__(256) void node_pre(
    const float* __restrict__ x,    // [NN,64]
    const float* __restrict__ W,    // [144,128]
    const float* __restrict__ bias, // [128]
    float* __restrict__ nt,         // [NN,128]
    float* __restrict__ yv)         // [NN,128]
{
    __shared__ float xs[8][64];     // 2 KB
    const int t  = threadIdx.x;
    const int nb = blockIdx.x * 8;  // 512 blocks x 8 nodes

    if (t < 128) {                  // stage 8 node rows (512 floats)
        int idx = t * 4;
        *(float4*)&xs[idx >> 6][idx & 63] = *(const float4*)&x[nb * 64 + idx];
    }
    __syncthreads();

    const int j = t & 127;          // output column
    const int h = t >> 7;           // node group (4 nodes each)
    float accN[4] = {0.f, 0.f, 0.f, 0.f};
    float accY[4] = {0.f, 0.f, 0.f, 0.f};

#pragma unroll 8
    for (int c = 0; c < 64; c++) {
        float wa = W[c * 128 + j];
        float wb = W[(64 + c) * 128 + j];
        float wd = wa - wb;
#pragma unroll
        for (int i = 0; i < 4; i++) {
            float xv = xs[h * 4 + i][c];        // LDS broadcast
            accN[i] = fmaf(xv, wd, accN[i]);
            accY[i] = fmaf(xv, wb, accY[i]);
        }
    }
    float bj = bias[j];
#pragma unroll
    for (int i = 0; i < 4; i++) {
        int node = nb + h * 4 + i;
        nt[node * 128 + j] = accN[i] + bj;
        yv[node * 128 + j] = accY[i];
    }
}

__global__ __launch_bounds__(256) void edge_max(
    const float* __restrict__ ea,   // [4,1024,1024,16]
    const float* __restrict__ W,    // [144,128]
    const int*   __restrict__ dst,  // [NN*KE]
    const float* __restrict__ nt,   // [NN,128]
    const float* __restrict__ yv,   // [NN,128]
    float* __restrict__ out)        // [NN,128]
{
    __shared__ int dstL[KE];
    __shared__ __align__(16) float eaL[KE][16];   // 2 KB
    __shared__ __align__(16) float red[4][128];   // 2 KB

    const int t    = threadIdx.x;
    const int n    = blockIdx.x;    // one block per node
    const int bidx = n >> 10;
    const int vi   = n & 1023;

    if (t < KE) dstL[t] = dst[n * KE + t];
    __syncthreads();

    if (t < 128) {                  // stage 32 eattr rows as float4
        int e  = t >> 2;
        int k4 = (t & 3) * 4;
        int ui = dstL[e] & 1023;
        *(float4*)&eaL[e][k4] =
            *(const float4*)&ea[(((size_t)bidx * 1024 + vi) * 1024 + ui) * 16 + k4];
    }

    const int cg = t & 31;          // 4 output cols: 4*cg..4*cg+3
    const int es = t >> 5;          // edge slice 0..7 (4 edges each)

    float4 wc[16];                  // Wc rows for this thread's 4 cols
#pragma unroll
    for (int k = 0; k < 16; k++)
        wc[k] = *(const float4*)&W[(128 + k) * 128 + cg * 4];

    __syncthreads();

    float4 vmax = {-FLT_MAX, -FLT_MAX, -FLT_MAX, -FLT_MAX};
#pragma unroll
    for (int ee = 0; ee < 4; ee++) {
        int e = es * 4 + ee;
        int d = dstL[e];
        float4 acc = *(const float4*)&yv[d * 128 + cg * 4];
#pragma unroll
        for (int kk = 0; kk < 4; kk++) {
            float4 e4 = *(const float4*)&eaL[e][kk * 4];   // ds_read_b128, broadcast
            acc.x = fmaf(e4.x, wc[kk*4+0].x, acc.x);
            acc.y = fmaf(e4.x, wc[kk*4+0].y, acc.y);
            acc.z = fmaf(e4.x, wc[kk*4+0].z, acc.z);
            acc.w = fmaf(e4.x, wc[kk*4+0].w, acc.w);
            acc.x = fmaf(e4.y, wc[kk*4+1].x, acc.x);
            acc.y = fmaf(e4.y, wc[kk*4+1].y, acc.y);
            acc.z = fmaf(e4.y, wc[kk*4+1].z, acc.z);
            acc.w = fmaf(e4.y, wc[kk*4+1].w, acc.w);
            acc.x = fmaf(e4.z, wc[kk*4+2].x, acc.x);
            acc.y = fmaf(e4.z, wc[kk*4+2].y, acc.y);
            acc.z = fmaf(e4.z, wc[kk*4+2].z, acc.z);
            acc.w = fmaf(e4.z, wc[kk*4+2].w, acc.w);
            acc.x = fmaf(e4.w, wc[kk*4+3].x, acc.x);
            acc.y = fmaf(e4.w, wc[kk*4+3].y, acc.y);
            acc.z = fmaf(e4.w, wc[kk*4+3].z, acc.z);
            acc.w = fmaf(e4.w, wc[kk*4+3].w, acc.w);
        }
        vmax.x = fmaxf(vmax.x, acc.x);
        vmax.y = fmaxf(vmax.y, acc.y);
        vmax.z = fmaxf(vmax.z, acc.z);
        vmax.w = fmaxf(vmax.w, acc.w);
    }

    // merge edge-slice pairs (es, es^1) in-register
    vmax.x = fmaxf(vmax.x, __shfl_xor(vmax.x, 32, 64));
    vmax.y = fmaxf(vmax.y, __shfl_xor(vmax.y, 32, 64));
    vmax.z = fmaxf(vmax.z, __shfl_xor(vmax.z, 32, 64));
    vmax.w = fmaxf(vmax.w, __shfl_xor(vmax.w, 32, 64));

    const int w = t >> 6;           // wave id: holds max over edges 8w..8w+7
    if ((t & 32) == 0)
        *(float4*)&red[w][cg * 4] = vmax;
    __syncthreads();

    if (t < 128) {
        float m = fmaxf(fmaxf(red[0][t], red[1][t]),
                        fmaxf(red[2][t], red[3][t]));
        out[n * 128 + t] = fmaxf(0.f, nt[n * 128 + t] + m);
    }
}

extern "C" void kernel_launch(void* const* d_in, const int* in_sizes, int n_in,
                              void* d_out, int out_size, void* d_ws, size_t ws_size,
                              hipStream_t stream) {
    const float* x    = (const float*)d_in[0];
    const float* ea   = (const float*)d_in[1];
    const float* W    = (const float*)d_in[2];
    const float* bias = (const float*)d_in[3];
    const int*   dst  = (const int*)d_in[5];
    float* out = (float*)d_out;

    float* nt = (float*)d_ws;                   // [NN,128] 2 MB
    float* yv = nt + (size_t)NN * OUTF;         // [NN,128] 2 MB

    hipLaunchKernelGGL(node_pre, dim3(512), dim3(256), 0, stream, x, W, bias, nt, yv);
    hipLaunchKernelGGL(edge_max, dim3(NN), dim3(256), 0, stream, ea, W, dst, nt, yv, out);
}